// Round 1
// baseline (27711.923 us; speedup 1.0000x reference)
//
#include <hip/hip_runtime.h>

#define NB 2048
#define NJ 23
#define NH 512
#define LN_EPS 1e-5f
#define RSQRT2 0.70710678118654752440f

// ---------- float2 helpers (avoid relying on operator overloads) ----------
__device__ __forceinline__ float2 f2(float x, float y){ float2 r; r.x=x; r.y=y; return r; }
__device__ __forceinline__ float2 f2s(float x){ return f2(x,x); }
__device__ __forceinline__ float2 add2(float2 a, float2 b){ return f2(a.x+b.x, a.y+b.y); }
__device__ __forceinline__ float2 fma2s(float s, float2 b, float2 c){ return f2(fmaf(s,b.x,c.x), fmaf(s,b.y,c.y)); }
__device__ __forceinline__ float gelu_f(float x){ return 0.5f*x*(1.0f+erff(x*RSQRT2)); }
__device__ __forceinline__ float2 gelu2(float2 v){ return f2(gelu_f(v.x), gelu_f(v.y)); }

__device__ __forceinline__ unsigned long long shfl_xor_u64(unsigned long long v, int m){
  int lo = __shfl_xor((int)(unsigned)(v & 0xffffffffULL), m);
  int hi = __shfl_xor((int)(unsigned)(v >> 32), m);
  return ((unsigned long long)(unsigned)hi << 32) | (unsigned long long)(unsigned)lo;
}

// ---------- row stats: mean + 1/sqrt(var+eps) for the 23 rows of xc ----------
// xc: per-thread float2 columns (cols 2t,2t+1). Uses Lbuf as transpose scratch.
__device__ __forceinline__ void row_stats(const float2* xc, float* Lbuf, float* mrs, int t){
  __syncthreads();                       // prior Lbuf readers done
  #pragma unroll
  for (int j=0;j<NJ;j++) *(float2*)(Lbuf + j*NH + 2*t) = xc[j];
  __syncthreads();
  int wv = t>>6, lane = t&63;
  for (int r = wv; r < NJ; r += 4){
    const float* row = Lbuf + r*NH;
    float4 v0 = *(const float4*)(row + lane*8);
    float4 v1 = *(const float4*)(row + lane*8 + 4);
    float s = v0.x+v0.y+v0.z+v0.w + v1.x+v1.y+v1.z+v1.w;
    #pragma unroll
    for (int o=32;o;o>>=1) s += __shfl_xor(s, o);
    float m = s * (1.0f/512.0f);
    float d, q = 0.f;
    d=v0.x-m; q+=d*d; d=v0.y-m; q+=d*d; d=v0.z-m; q+=d*d; d=v0.w-m; q+=d*d;
    d=v1.x-m; q+=d*d; d=v1.y-m; q+=d*d; d=v1.z-m; q+=d*d; d=v1.w-m; q+=d*d;
    #pragma unroll
    for (int o=32;o;o>>=1) q += __shfl_xor(q, o);
    if (lane==0){
      mrs[r] = m;
      mrs[NJ+r] = 1.0f / sqrtf(q*(1.0f/512.0f) + LN_EPS);
    }
  }
  __syncthreads();
}

// ---------- acc[j] += sum_h Lbuf[j][h] * w[h*512] (w pre-offset to this thread's 2 cols)
__device__ __forceinline__ void gemm_bcast(float2* acc, const float* __restrict__ Lbuf,
                                           const float* __restrict__ wcol){
  for (int h=0; h<NH; h+=4){
    float2 w0 = *(const float2*)(wcol + (h+0)*NH);
    float2 w1 = *(const float2*)(wcol + (h+1)*NH);
    float2 w2 = *(const float2*)(wcol + (h+2)*NH);
    float2 w3 = *(const float2*)(wcol + (h+3)*NH);
    #pragma unroll
    for (int j=0;j<NJ;j++){
      float4 z4 = *(const float4*)(Lbuf + j*NH + h);
      float2 a = acc[j];
      a = fma2s(z4.x, w0, a);
      a = fma2s(z4.y, w1, a);
      a = fma2s(z4.z, w2, a);
      a = fma2s(z4.w, w3, a);
      acc[j] = a;
    }
  }
}

// ---------- one PCT mixer layer, xc = residual (float2 per thread, 23 rows) ----------
__device__ __forceinline__ void mixer_layer(float2* xc, int t,
    float* Lbuf, float* tw1s, float* tw2s, float* mrs,
    const float* __restrict__ ln1, const float* __restrict__ tw1, const float* __restrict__ tb1,
    const float* __restrict__ tw2, const float* __restrict__ tb2,
    const float* __restrict__ ln2, const float* __restrict__ cw1, const float* __restrict__ cb1,
    const float* __restrict__ cw2, const float* __restrict__ cb2)
{
  int h2 = 2*t;
  // stage token weights for this layer (visibility covered by row_stats barriers)
  for (int i=t; i<NJ*64; i+=256) tw1s[i] = tw1[i];
  for (int i=t; i<64*NJ; i+=256) tw2s[i] = tw2[i];
  // ---- LN1 stats, token-mixing MLP (per-column, register resident) ----
  row_stats(xc, Lbuf, mrs, t);
  float2 g1 = *(const float2*)(ln1 + h2);
  float2 b1 = *(const float2*)(ln1 + NH + h2);
  float2 yacc[NJ];
  #pragma unroll
  for (int j=0;j<NJ;j++) yacc[j] = f2s(tb2[j]);
  for (int c=0;c<64;c+=16){
    float2 u[16];
    #pragma unroll
    for (int i=0;i<16;i++) u[i] = f2s(tb1[c+i]);
    #pragma unroll
    for (int j=0;j<NJ;j++){
      float m = mrs[j], rs = mrs[NJ+j];
      float2 tc = f2(fmaf((xc[j].x-m)*rs, g1.x, b1.x), fmaf((xc[j].y-m)*rs, g1.y, b1.y));
      #pragma unroll
      for (int i=0;i<16;i++) u[i] = fma2s(tw1s[j*64+c+i], tc, u[i]);
    }
    #pragma unroll
    for (int i=0;i<16;i++){
      float2 gu = gelu2(u[i]);
      #pragma unroll
      for (int j=0;j<NJ;j++) yacc[j] = fma2s(tw2s[(c+i)*NJ+j], gu, yacc[j]);
    }
  }
  #pragma unroll
  for (int j=0;j<NJ;j++) xc[j] = add2(xc[j], yacc[j]);   // xc = x + y
  // ---- LN2 + channel MLP ----
  row_stats(xc, Lbuf, mrs, t);
  float2 g2 = *(const float2*)(ln2 + h2);
  float2 b2v = *(const float2*)(ln2 + NH + h2);
  #pragma unroll
  for (int j=0;j<NJ;j++){
    float m = mrs[j], rs = mrs[NJ+j];
    *(float2*)(Lbuf + j*NH + h2) = f2(fmaf((xc[j].x-m)*rs, g2.x, b2v.x),
                                      fmaf((xc[j].y-m)*rs, g2.y, b2v.y));
  }
  __syncthreads();
  float2 acc[NJ];
  { float2 cb = *(const float2*)(cb1 + h2);
    #pragma unroll
    for (int j=0;j<NJ;j++) acc[j] = cb; }
  gemm_bcast(acc, Lbuf, cw1 + h2);
  __syncthreads();                        // all GEMM1 reads done
  #pragma unroll
  for (int j=0;j<NJ;j++) *(float2*)(Lbuf + j*NH + h2) = gelu2(acc[j]);
  __syncthreads();
  { float2 cb = *(const float2*)(cb2 + h2);
    #pragma unroll
    for (int j=0;j<NJ;j++) acc[j] = cb; }
  gemm_bcast(acc, Lbuf, cw2 + h2);
  #pragma unroll
  for (int j=0;j<NJ;j++) xc[j] = add2(xc[j], acc[j]);    // xc = x + y + z
}

// ================= encoder =================
__global__ __launch_bounds__(256, 2) void pct_enc_kernel(
  const float* __restrict__ pose, const float* __restrict__ start_w, const float* __restrict__ start_b,
  const float* __restrict__ ln1a, const float* __restrict__ tw1a, const float* __restrict__ tb1a,
  const float* __restrict__ tw2a, const float* __restrict__ tb2a, const float* __restrict__ ln2a,
  const float* __restrict__ cw1a, const float* __restrict__ cb1a, const float* __restrict__ cw2a,
  const float* __restrict__ cb2a, const float* __restrict__ lnf, const float* __restrict__ tok_w,
  const float* __restrict__ tok_b, const float* __restrict__ feat_w, const float* __restrict__ feat_b,
  float* __restrict__ e_out)
{
  __shared__ float Lbuf[NJ*NH];
  __shared__ float tw1s[NJ*64];
  __shared__ float tw2s[64*NJ];
  __shared__ float mrs[2*NJ];
  __shared__ float tokws[NJ*NJ];
  __shared__ float tokbs[NJ];
  __shared__ float psm[NJ*9+1];
  int t = threadIdx.x, b = blockIdx.x, h2 = 2*t;
  if (t < NJ*9) psm[t] = pose[b*NJ*9 + t];
  for (int i=t;i<NJ*NJ;i+=256) tokws[i] = tok_w[i];
  if (t<NJ) tokbs[t] = tok_b[t];
  __syncthreads();
  float2 xc[NJ];
  {
    float2 sb = *(const float2*)(start_b + h2);
    #pragma unroll
    for (int j=0;j<NJ;j++) xc[j]=sb;
    #pragma unroll
    for (int c=0;c<9;c++){
      float2 w = *(const float2*)(start_w + c*NH + h2);
      #pragma unroll
      for (int j=0;j<NJ;j++) xc[j] = fma2s(psm[j*9+c], w, xc[j]);
    }
  }
  for (int l=0;l<4;l++){
    mixer_layer(xc, t, Lbuf, tw1s, tw2s, mrs,
      ln1a + l*1024, tw1a + l*(NJ*64), tb1a + l*64, tw2a + l*(64*NJ), tb2a + l*NJ,
      ln2a + l*1024, cw1a + l*(NH*NH), cb1a + l*NH, cw2a + l*(NH*NH), cb2a + l*NH);
  }
  // final LN + token projection (tok_w over J) applied per column
  row_stats(xc, Lbuf, mrs, t);
  float2 gF = *(const float2*)(lnf + h2);
  float2 bF = *(const float2*)(lnf + NH + h2);
  float2 xt[NJ];
  #pragma unroll
  for (int j=0;j<NJ;j++) xt[j] = f2s(tokbs[j]);
  #pragma unroll
  for (int jp=0;jp<NJ;jp++){
    float m = mrs[jp], rs = mrs[NJ+jp];
    float2 v = f2(fmaf((xc[jp].x-m)*rs, gF.x, bF.x), fmaf((xc[jp].y-m)*rs, gF.y, bF.y));
    #pragma unroll
    for (int j=0;j<NJ;j++) xt[j] = fma2s(tokws[jp*NJ+j], v, xt[j]);
  }
  __syncthreads();
  #pragma unroll
  for (int j=0;j<NJ;j++) *(float2*)(Lbuf + j*NH + h2) = xt[j];
  __syncthreads();
  float2 acc[NJ];
  { float2 fb = *(const float2*)(feat_b + h2);
    #pragma unroll
    for (int j=0;j<NJ;j++) acc[j]=fb; }
  gemm_bcast(acc, Lbuf, feat_w + h2);
  #pragma unroll
  for (int j=0;j<NJ;j++) *(float2*)(e_out + (size_t)(b*NJ+j)*NH + h2) = acc[j];
}

// ================= norms =================
__global__ void pct_norm_kernel(const float* __restrict__ e, const float* __restrict__ cb,
                                float* __restrict__ enorm, float* __restrict__ cnorm){
  int gw = (blockIdx.x*256 + threadIdx.x)>>6;
  int lane = threadIdx.x & 63;
  int nw = gridDim.x*4;
  for (int r = gw; r < 2048 + 47104; r += nw){
    const float* src = (r < 2048) ? (cb + (size_t)r*512) : (e + (size_t)(r-2048)*512);
    float4 v0 = *(const float4*)(src + lane*8);
    float4 v1 = *(const float4*)(src + lane*8 + 4);
    float q = v0.x*v0.x+v0.y*v0.y+v0.z*v0.z+v0.w*v0.w
            + v1.x*v1.x+v1.y*v1.y+v1.z*v1.z+v1.w*v1.w;
    #pragma unroll
    for (int o=32;o;o>>=1) q += __shfl_xor(q, o);
    if (lane==0){ if (r<2048) cnorm[r]=q; else enorm[r-2048]=q; }
  }
}

// ================= VQ distance GEMM + fused argmin =================
#define VBM 64
#define VBN 128
#define VBK 32
#define ETS 68
#define CTS 132
__global__ __launch_bounds__(256, 4) void pct_vq_kernel(
  const float* __restrict__ e, const float* __restrict__ cb,
  const float* __restrict__ enorm, const float* __restrict__ cnorm,
  unsigned long long* __restrict__ packed)
{
  __shared__ float Et[VBK*ETS];
  __shared__ float Ct[VBK*CTS];
  int t = threadIdx.x;
  int row0 = blockIdx.x * VBM;
  int n00  = blockIdx.y * VBN;
  int m0 = (t>>4)<<2;
  int n0 = (t&15)<<3;
  float2 acc[2][8];
  #pragma unroll
  for (int p=0;p<2;p++)
    #pragma unroll
    for (int j=0;j<8;j++) acc[p][j] = f2s(0.f);
  int er = t>>2, eq = t&3;
  int cn = t>>1, ch = t&1;
  for (int kc=0; kc<512; kc+=VBK){
    __syncthreads();
    {
      const float4* src = (const float4*)(e + (size_t)(row0+er)*512 + kc + eq*8);
      float4 a = src[0], bv = src[1];
      float* d0 = Et + (eq*8)*ETS + er;
      d0[0*ETS]=a.x;  d0[1*ETS]=a.y;  d0[2*ETS]=a.z;  d0[3*ETS]=a.w;
      d0[4*ETS]=bv.x; d0[5*ETS]=bv.y; d0[6*ETS]=bv.z; d0[7*ETS]=bv.w;
    }
    {
      const float4* src = (const float4*)(cb + (size_t)(n00+cn)*512 + kc + ch*16);
      float4 a=src[0], b2=src[1], c2=src[2], d2=src[3];
      float* d0 = Ct + (ch*16)*CTS + cn;
      d0[0*CTS]=a.x;   d0[1*CTS]=a.y;   d0[2*CTS]=a.z;   d0[3*CTS]=a.w;
      d0[4*CTS]=b2.x;  d0[5*CTS]=b2.y;  d0[6*CTS]=b2.z;  d0[7*CTS]=b2.w;
      d0[8*CTS]=c2.x;  d0[9*CTS]=c2.y;  d0[10*CTS]=c2.z; d0[11*CTS]=c2.w;
      d0[12*CTS]=d2.x; d0[13*CTS]=d2.y; d0[14*CTS]=d2.z; d0[15*CTS]=d2.w;
    }
    __syncthreads();
    #pragma unroll 8
    for (int k=0;k<VBK;k++){
      float4 av = *(const float4*)(Et + k*ETS + m0);
      float4 b0 = *(const float4*)(Ct + k*CTS + n0);
      float4 b1 = *(const float4*)(Ct + k*CTS + n0 + 4);
      float2 a01 = f2(av.x, av.y), a23 = f2(av.z, av.w);
      float bs[8] = {b0.x,b0.y,b0.z,b0.w,b1.x,b1.y,b1.z,b1.w};
      #pragma unroll
      for (int j=0;j<8;j++){
        acc[0][j] = fma2s(bs[j], a01, acc[0][j]);
        acc[1][j] = fma2s(bs[j], a23, acc[1][j]);
      }
    }
  }
  unsigned long long key[4];
  #pragma unroll
  for (int i=0;i<4;i++){
    float en = enorm[row0 + m0 + i];
    unsigned long long kk = ~0ULL;
    #pragma unroll
    for (int j=0;j<8;j++){
      float2 av = acc[i>>1][j];
      float dot = (i&1) ? av.y : av.x;
      int code = n00 + n0 + j;
      float dd = (en + cnorm[code]) - 2.0f*dot;
      unsigned long long kv = ((unsigned long long)__float_as_uint(dd)<<32) | (unsigned long long)(unsigned)code;
      kk = kv < kk ? kv : kk;
    }
    key[i] = kk;
  }
  #pragma unroll
  for (int o=1;o<16;o<<=1){
    #pragma unroll
    for (int i=0;i<4;i++){
      unsigned long long other = shfl_xor_u64(key[i], o);
      key[i] = other < key[i] ? other : key[i];
    }
  }
  if ((t&15)==0){
    #pragma unroll
    for (int i=0;i<4;i++) atomicMin(packed + row0 + m0 + i, key[i]);
  }
}

// ================= idx output + latent loss =================
__global__ void pct_loss_idx_kernel(const float* __restrict__ e, const float* __restrict__ cb,
                                    const unsigned long long* __restrict__ packed,
                                    float* __restrict__ idx_out, float* __restrict__ partials){
  int t = threadIdx.x, lane = t&63;
  int gw = (blockIdx.x*256 + t)>>6;
  int nw = gridDim.x*4;
  float part = 0.f;
  for (int r=gw; r<47104; r+=nw){
    unsigned long long pk = packed[r];
    int idx = (int)(unsigned)(pk & 0xffffffffULL);
    if (lane==0) idx_out[r] = (float)idx;
    const float4* ep = (const float4*)(e + (size_t)r*512);
    const float4* cp = (const float4*)(cb + (size_t)idx*512);
    #pragma unroll
    for (int i=0;i<2;i++){
      float4 ev = ep[lane*2+i], cv = cp[lane*2+i];
      float dx=cv.x-ev.x, dy=cv.y-ev.y, dz=cv.z-ev.z, dw=cv.w-ev.w;
      part += dx*dx+dy*dy+dz*dz+dw*dw;
    }
  }
  #pragma unroll
  for (int o=32;o;o>>=1) part += __shfl_xor(part, o);
  __shared__ float wsum[4];
  if (lane==0) wsum[t>>6] = part;
  __syncthreads();
  if (t==0) partials[blockIdx.x] = wsum[0]+wsum[1]+wsum[2]+wsum[3];
}

__global__ void pct_loss_final_kernel(const float* __restrict__ partials, float* __restrict__ loss){
  float s=0.f;
  for (int i=threadIdx.x; i<256; i+=64) s += partials[i];
  #pragma unroll
  for (int o=32;o;o>>=1) s += __shfl_xor(s, o);
  if (threadIdx.x==0) *loss = s * (1.0f/(47104.0f*512.0f));
}

// ================= decoder =================
__global__ __launch_bounds__(256, 2) void pct_dec_kernel(
  const unsigned long long* __restrict__ packed, const float* __restrict__ codebook,
  const float* __restrict__ dtok_w, const float* __restrict__ dtok_b,
  const float* __restrict__ dstart_w, const float* __restrict__ dstart_b,
  const float* __restrict__ ln1a, const float* __restrict__ tw1a, const float* __restrict__ tb1a,
  const float* __restrict__ tw2a, const float* __restrict__ tb2a, const float* __restrict__ ln2a,
  const float* __restrict__ cw1a, const float* __restrict__ cb1a, const float* __restrict__ cw2a,
  const float* __restrict__ cb2a, const float* __restrict__ lnfd,
  const float* __restrict__ rec_w, const float* __restrict__ rec_b,
  float* __restrict__ rec_out)
{
  __shared__ float Lbuf[NJ*NH];
  __shared__ float tw1s[NJ*64];
  __shared__ float tw2s[64*NJ];
  __shared__ float mrs[2*NJ];
  __shared__ float tokws[NJ*NJ];
  __shared__ float tokbs[NJ];
  __shared__ int   idxs[NJ];
  int t = threadIdx.x, b = blockIdx.x, h2 = 2*t;
  if (t<NJ) idxs[t] = (int)(unsigned)(packed[b*NJ+t] & 0xffffffffULL);
  for (int i=t;i<NJ*NJ;i+=256) tokws[i] = dtok_w[i];
  if (t<NJ) tokbs[t] = dtok_b[t];
  __syncthreads();
  // gather q columns, token projection over J (no LN)
  float2 xt[NJ];
  #pragma unroll
  for (int j=0;j<NJ;j++) xt[j] = f2s(tokbs[j]);
  #pragma unroll
  for (int jp=0;jp<NJ;jp++){
    float2 qv = *(const float2*)(codebook + (size_t)idxs[jp]*512 + h2);
    #pragma unroll
    for (int j=0;j<NJ;j++) xt[j] = fma2s(tokws[jp*NJ+j], qv, xt[j]);
  }
  #pragma unroll
  for (int j=0;j<NJ;j++) *(float2*)(Lbuf + j*NH + h2) = xt[j];
  __syncthreads();
  float2 xc[NJ];
  { float2 sb = *(const float2*)(dstart_b + h2);
    #pragma unroll
    for (int j=0;j<NJ;j++) xc[j]=sb; }
  gemm_bcast(xc, Lbuf, dstart_w + h2);
  for (int l=0;l<4;l++){
    mixer_layer(xc, t, Lbuf, tw1s, tw2s, mrs,
      ln1a + l*1024, tw1a + l*(NJ*64), tb1a + l*64, tw2a + l*(64*NJ), tb2a + l*NJ,
      ln2a + l*1024, cw1a + l*(NH*NH), cb1a + l*NH, cw2a + l*(NH*NH), cb2a + l*NH);
  }
  row_stats(xc, Lbuf, mrs, t);
  float2 gF = *(const float2*)(lnfd + h2);
  float2 bF = *(const float2*)(lnfd + NH + h2);
  #pragma unroll
  for (int j=0;j<NJ;j++){
    float m = mrs[j], rs = mrs[NJ+j];
    *(float2*)(Lbuf + j*NH + h2) = f2(fmaf((xc[j].x-m)*rs, gF.x, bF.x),
                                      fmaf((xc[j].y-m)*rs, gF.y, bF.y));
  }
  __syncthreads();
  if (t < NJ*9){
    int j = t/9, c = t - j*9;
    float a = rec_b[c];
    const float* row = Lbuf + j*NH;
    for (int h=0;h<NH;h++) a = fmaf(row[h], rec_w[h*9+c], a);
    rec_out[(size_t)(b*NJ+j)*9 + c] = a;
  }
}

// ================= launch =================
extern "C" void kernel_launch(void* const* d_in, const int* in_sizes, int n_in,
                              void* d_out, int out_size, void* d_ws, size_t ws_size,
                              hipStream_t stream) {
  (void)in_sizes; (void)n_in; (void)out_size; (void)ws_size;
  const float* pose        = (const float*)d_in[0];
  const float* start_w     = (const float*)d_in[1];
  const float* start_b     = (const float*)d_in[2];
  const float* enc_ln1     = (const float*)d_in[3];
  const float* enc_tw1     = (const float*)d_in[4];
  const float* enc_tb1     = (const float*)d_in[5];
  const float* enc_tw2     = (const float*)d_in[6];
  const float* enc_tb2     = (const float*)d_in[7];
  const float* enc_ln2     = (const float*)d_in[8];
  const float* enc_cw1     = (const float*)d_in[9];
  const float* enc_cb1     = (const float*)d_in[10];
  const float* enc_cw2     = (const float*)d_in[11];
  const float* enc_cb2     = (const float*)d_in[12];
  const float* enc_lnf     = (const float*)d_in[13];
  const float* tok_w       = (const float*)d_in[14];
  const float* tok_b       = (const float*)d_in[15];
  const float* feat_w      = (const float*)d_in[16];
  const float* feat_b      = (const float*)d_in[17];
  const float* codebook    = (const float*)d_in[18];
  const float* dec_tok_w   = (const float*)d_in[19];
  const float* dec_tok_b   = (const float*)d_in[20];
  const float* dec_start_w = (const float*)d_in[21];
  const float* dec_start_b = (const float*)d_in[22];
  const float* dec_ln1     = (const float*)d_in[23];
  const float* dec_tw1     = (const float*)d_in[24];
  const float* dec_tb1     = (const float*)d_in[25];
  const float* dec_tw2     = (const float*)d_in[26];
  const float* dec_tb2     = (const float*)d_in[27];
  const float* dec_ln2     = (const float*)d_in[28];
  const float* dec_cw1     = (const float*)d_in[29];
  const float* dec_cb1     = (const float*)d_in[30];
  const float* dec_cw2     = (const float*)d_in[31];
  const float* dec_cb2     = (const float*)d_in[32];
  const float* dec_lnf     = (const float*)d_in[33];
  const float* rec_w       = (const float*)d_in[34];
  const float* rec_b       = (const float*)d_in[35];

  // workspace layout
  float* e = (float*)d_ws;                                            // 47104*512 f32
  unsigned long long* packed = (unsigned long long*)((char*)d_ws + (size_t)47104*512*4);
  float* cnorm = (float*)((char*)packed + (size_t)47104*8);           // 2048
  float* enormp = cnorm + 2048;                                       // 47104
  float* partials = enormp + 47104;                                   // 256

  float* rec_out  = (float*)d_out;                 // 423936
  float* idx_out  = rec_out + 423936;              // 47104
  float* loss_out = idx_out + 47104;               // 1

  hipMemsetAsync(packed, 0xFF, (size_t)47104*8, stream);

  pct_enc_kernel<<<NB, 256, 0, stream>>>(pose, start_w, start_b,
    enc_ln1, enc_tw1, enc_tb1, enc_tw2, enc_tb2, enc_ln2,
    enc_cw1, enc_cb1, enc_cw2, enc_cb2, enc_lnf, tok_w, tok_b, feat_w, feat_b, e);

  pct_norm_kernel<<<192, 256, 0, stream>>>(e, codebook, enormp, cnorm);

  pct_vq_kernel<<<dim3(736,16), 256, 0, stream>>>(e, codebook, enormp, cnorm, packed);

  pct_loss_idx_kernel<<<256, 256, 0, stream>>>(e, codebook, packed, idx_out, partials);
  pct_loss_final_kernel<<<1, 64, 0, stream>>>(partials, loss_out);

  pct_dec_kernel<<<NB, 256, 0, stream>>>(packed, codebook,
    dec_tok_w, dec_tok_b, dec_start_w, dec_start_b,
    dec_ln1, dec_tw1, dec_tb1, dec_tw2, dec_tb2, dec_ln2,
    dec_cw1, dec_cb1, dec_cw2, dec_cb2, dec_lnf, rec_w, rec_b, rec_out);
}